// Round 2
// baseline (2824.879 us; speedup 1.0000x reference)
//
#include <hip/hip_runtime.h>
#include <hip/hip_bf16.h>

#define NEG_SLOPE 0.2f

// ---------------------------------------------------------------------------
// All float tensors are fp32 (per the reference dtypes). edge_index is int32.
//
// Layer 1 collapses because IN==1:
//   h1[n,h,c] = x[n] * W1[h,c]
//   logit_src[n,h] = x[n] * S1[h],  S1[h] = sum_c W1[h,c]*a_src1[h,c]
//   logit_dst[n,h] = x[n] * D1[h]
//   aggregated out1[n,h,c] = W1[h,c] * t1[n,h],  t1 = sum_e alpha * x[src]
// No max-subtraction needed: |logit| <~ 30 -> exp safe in fp32.
//
// ws layout (floats):
//   [0..15]           consts: S1[0..3], D1[0..3]
//   [16 .. +4N)       s1   softmax denom L1   (zeroed)
//   [.. +4N)          t1   weighted x sum L1  (zeroed)
//   [.. +8N)          h2   layer2 features
//   [.. +N)           als2 layer2 src logits
//   [.. +N)           ald2 layer2 dst logits
//   [.. +N)           s2   softmax denom L2   (zeroed)
//   [.. +8N)          acc2 weighted feat sum  (zeroed)
// total = 16 + 27N floats (~10.8 MB @ N=100000)
// ---------------------------------------------------------------------------

__global__ void prep_consts(const float* __restrict__ W1,
                            const float* __restrict__ as1,
                            const float* __restrict__ ad1,
                            float* __restrict__ consts) {
    int t = threadIdx.x;          // 0..7 used
    if (t >= 8) return;
    int h = t & 3;
    const float* a = (t < 4) ? as1 : ad1;
    float s = 0.f;
    #pragma unroll
    for (int c = 0; c < 8; ++c)
        s += W1[h * 8 + c] * a[h * 8 + c];
    consts[t] = s;
}

// Layer-1 edge pass: per edge, 4 heads, accumulate exp-logit and exp*x[src].
__global__ void edge_pass1(const int* __restrict__ ei,
                           const float* __restrict__ x,
                           const float* __restrict__ consts,
                           float* __restrict__ s1, float* __restrict__ t1,
                           int E, int N) {
    int e = blockIdx.x * blockDim.x + threadIdx.x;
    if (e >= E + N) return;
    int src, dst;
    if (e < E) { src = ei[e]; dst = ei[E + e]; }
    else       { src = dst = e - E; }
    float xs = x[src];
    float xd = x[dst];
    #pragma unroll
    for (int h = 0; h < 4; ++h) {
        float v = xs * consts[h] + xd * consts[4 + h];
        v = (v > 0.f) ? v : NEG_SLOPE * v;
        float w = __expf(v);                 // |v| bounded, no max-sub needed
        atomicAdd(&s1[dst * 4 + h], w);
        atomicAdd(&t1[dst * 4 + h], w * xs);
    }
}

// Node pass: layer-1 epilogue (normalize, *W1 + b1, ReLU), h2 = r @ W2,
// and layer-2 per-node logits.
__global__ void node_mid(const float* __restrict__ s1, const float* __restrict__ t1,
                         const float* __restrict__ W1,
                         const float* __restrict__ b1,
                         const float* __restrict__ W2,
                         const float* __restrict__ as2,
                         const float* __restrict__ ad2,
                         float* __restrict__ h2,
                         float* __restrict__ als2, float* __restrict__ ald2,
                         int N) {
    int n = blockIdx.x * blockDim.x + threadIdx.x;
    if (n >= N) return;
    float r[32];
    #pragma unroll
    for (int h = 0; h < 4; ++h) {
        float t = t1[n * 4 + h] / s1[n * 4 + h];
        #pragma unroll
        for (int c = 0; c < 8; ++c) {
            float v = t * W1[h * 8 + c] + b1[h * 8 + c];
            r[h * 8 + c] = fmaxf(v, 0.f);
        }
    }
    float o[8];
    #pragma unroll
    for (int c = 0; c < 8; ++c) o[c] = 0.f;
    #pragma unroll
    for (int k = 0; k < 32; ++k) {
        float rv = r[k];
        #pragma unroll
        for (int c = 0; c < 8; ++c) o[c] += rv * W2[k * 8 + c];
    }
    float as = 0.f, ad = 0.f;
    #pragma unroll
    for (int c = 0; c < 8; ++c) {
        h2[n * 8 + c] = o[c];
        as += o[c] * as2[c];
        ad += o[c] * ad2[c];
    }
    als2[n] = as;
    ald2[n] = ad;
}

// Layer-2 edge pass: single head, 8 channels. h2 gathered as 2x float4.
__global__ void edge_pass2(const int* __restrict__ ei,
                           const float* __restrict__ als2,
                           const float* __restrict__ ald2,
                           const float* __restrict__ h2,
                           float* __restrict__ s2, float* __restrict__ acc2,
                           int E, int N) {
    int e = blockIdx.x * blockDim.x + threadIdx.x;
    if (e >= E + N) return;
    int src, dst;
    if (e < E) { src = ei[e]; dst = ei[E + e]; }
    else       { src = dst = e - E; }
    float v = als2[src] + ald2[dst];
    v = (v > 0.f) ? v : NEG_SLOPE * v;
    float w = __expf(v);
    atomicAdd(&s2[dst], w);
    const float4* hs = (const float4*)&h2[src * 8];
    float4 a = hs[0], b = hs[1];
    float* acc = &acc2[dst * 8];
    atomicAdd(&acc[0], w * a.x);
    atomicAdd(&acc[1], w * a.y);
    atomicAdd(&acc[2], w * a.z);
    atomicAdd(&acc[3], w * a.w);
    atomicAdd(&acc[4], w * b.x);
    atomicAdd(&acc[5], w * b.y);
    atomicAdd(&acc[6], w * b.z);
    atomicAdd(&acc[7], w * b.w);
}

// Final epilogue: out[n,c] = acc2[n,c]/s2[n] + b2[c].
__global__ void node_out(const float* __restrict__ s2, const float* __restrict__ acc2,
                         const float* __restrict__ b2,
                         float* __restrict__ out, int N) {
    int i = blockIdx.x * blockDim.x + threadIdx.x;
    if (i >= N * 8) return;
    int n = i >> 3;
    int c = i & 7;
    out[i] = acc2[i] / s2[n] + b2[c];
}

extern "C" void kernel_launch(void* const* d_in, const int* in_sizes, int n_in,
                              void* d_out, int out_size, void* d_ws, size_t ws_size,
                              hipStream_t stream) {
    const float* x   = (const float*)d_in[0];
    const int*   ei  = (const int*)d_in[1];
    const float* W1  = (const float*)d_in[2];
    const float* as1 = (const float*)d_in[3];
    const float* ad1 = (const float*)d_in[4];
    const float* b1  = (const float*)d_in[5];
    const float* W2  = (const float*)d_in[6];
    const float* as2 = (const float*)d_in[7];
    const float* ad2 = (const float*)d_in[8];
    const float* b2  = (const float*)d_in[9];
    float* out = (float*)d_out;

    const int N = in_sizes[0];          // 100000 (x is N x 1)
    const int E = in_sizes[1] / 2;      // 3200000

    float* ws     = (float*)d_ws;
    float* consts = ws;                  // 16 floats
    float* s1     = ws + 16;             // 4N
    float* t1     = s1 + 4 * (size_t)N;  // 4N
    float* h2     = t1 + 4 * (size_t)N;  // 8N
    float* als2   = h2 + 8 * (size_t)N;  // N
    float* ald2   = als2 + (size_t)N;    // N
    float* s2     = ald2 + (size_t)N;    // N
    float* acc2   = s2 + (size_t)N;      // 8N

    // Zero accumulation regions (ws is re-poisoned 0xAA before each call).
    hipMemsetAsync(ws, 0, (16 + 8 * (size_t)N) * sizeof(float), stream); // consts+s1+t1
    hipMemsetAsync(s2, 0, 9 * (size_t)N * sizeof(float), stream);        // s2+acc2

    prep_consts<<<1, 64, 0, stream>>>(W1, as1, ad1, consts);

    int total = E + N;
    int blkE = 256;
    edge_pass1<<<(total + blkE - 1) / blkE, blkE, 0, stream>>>(ei, x, consts, s1, t1, E, N);

    node_mid<<<(N + 255) / 256, 256, 0, stream>>>(s1, t1, W1, b1, W2, as2, ad2,
                                                  h2, als2, ald2, N);

    edge_pass2<<<(total + blkE - 1) / blkE, blkE, 0, stream>>>(ei, als2, ald2, h2,
                                                               s2, acc2, E, N);

    node_out<<<(N * 8 + 255) / 256, 256, 0, stream>>>(s2, acc2, b2, out, N);
}

// Round 3
// 605.701 us; speedup vs baseline: 4.6638x; 4.6638x over previous
//
#include <hip/hip_runtime.h>
#include <hip/hip_bf16.h>

#define NEG_SLOPE 0.2f

// ---------------------------------------------------------------------------
// GAT 2-layer, N=100k nodes, E=3.2M edges (+N self-loops, handled analytically).
//
// Layer 1 collapses because IN==1:
//   logit_src[n,h] = x[n]*S1[h], logit_dst[n,h] = x[n]*D1[h]
//   out1[n,h,c] = W1[h,c] * t1[n,h] + b1,  t1 = (sum_e w*x[src]) / (sum_e w)
//
// R3 strategy: counting-sort edges by dst into CSR (6.4M int atomics),
// then per-node pull aggregation with ZERO atomics (was 56M fp32 atomics,
// each a ~32B memory-side RMW -> 1.75 GB write traffic, 21 G atomics/s bound).
//
// ws layout (4B units):
//   [0..15]        consts  S1[4], D1[4]
//   [16, +N)       off     CSR start offsets
//   [+N)           cursor  scatter cursors; == CSR end after scatter
//   [+N)           als2    layer2 src logits
//   [+N)           ald2    layer2 dst logits
//   [+8N)          h2      layer2 features (first N aliased as deg during build)
//   [+1024)        partial block partial sums for scan
//   [+E)           sorted_src
// total = 16 + 12N + 1024 + E elems (~17.6 MB). Fallback to atomic path if
// ws_size is too small (R2 layout, 10.8 MB, known to fit).
// ---------------------------------------------------------------------------

__global__ void prep_consts(const float* __restrict__ W1,
                            const float* __restrict__ as1,
                            const float* __restrict__ ad1,
                            float* __restrict__ consts) {
    int t = threadIdx.x;
    if (t >= 8) return;
    int h = t & 3;
    const float* a = (t < 4) ? as1 : ad1;
    float s = 0.f;
    #pragma unroll
    for (int c = 0; c < 8; ++c)
        s += W1[h * 8 + c] * a[h * 8 + c];
    consts[t] = s;
}

// ---------------- CSR build ----------------

__global__ void hist_kernel(const int* __restrict__ ei, int* __restrict__ deg, int E) {
    int e = blockIdx.x * blockDim.x + threadIdx.x;
    if (e >= E) return;
    atomicAdd(&deg[ei[E + e]], 1);
}

__global__ void scan_block_sums(const int* __restrict__ deg, int* __restrict__ partial, int N) {
    __shared__ int sh[256];
    int t = threadIdx.x;
    int i = blockIdx.x * 256 + t;
    sh[t] = (i < N) ? deg[i] : 0;
    __syncthreads();
    #pragma unroll
    for (int o = 128; o > 0; o >>= 1) {
        if (t < o) sh[t] += sh[t + o];
        __syncthreads();
    }
    if (t == 0) partial[blockIdx.x] = sh[0];
}

// single block of 512; nb <= 512 required (guaranteed by host fallback check)
__global__ void scan_partials(int* __restrict__ partial, int nb) {
    __shared__ int buf[512];
    int t = threadIdx.x;
    int orig = (t < nb) ? partial[t] : 0;
    buf[t] = orig;
    __syncthreads();
    for (int o = 1; o < 512; o <<= 1) {
        int add = (t >= o) ? buf[t - o] : 0;
        __syncthreads();
        buf[t] += add;
        __syncthreads();
    }
    if (t < nb) partial[t] = buf[t] - orig;   // exclusive
}

__global__ void scan_apply(const int* __restrict__ deg, const int* __restrict__ partial,
                           int* __restrict__ off, int* __restrict__ cursor, int N) {
    __shared__ int buf[256];
    int t = threadIdx.x;
    int i = blockIdx.x * 256 + t;
    int orig = (i < N) ? deg[i] : 0;
    buf[t] = orig;
    __syncthreads();
    for (int o = 1; o < 256; o <<= 1) {
        int add = (t >= o) ? buf[t - o] : 0;
        __syncthreads();
        buf[t] += add;
        __syncthreads();
    }
    int excl = buf[t] - orig + partial[blockIdx.x];
    if (i < N) { off[i] = excl; cursor[i] = excl; }
}

__global__ void scatter_edges(const int* __restrict__ ei, int* __restrict__ cursor,
                              int* __restrict__ ssrc, int E) {
    int e = blockIdx.x * blockDim.x + threadIdx.x;
    if (e >= E) return;
    int s = ei[e], d = ei[E + e];
    int pos = atomicAdd(&cursor[d], 1);
    ssrc[pos] = s;
}

// ---------------- fused per-node passes (no atomics) ----------------

// Layer 1 aggregation + epilogue + layer-2 transform + layer-2 logits.
__global__ void l1_fused(const float* __restrict__ x,
                         const int* __restrict__ off, const int* __restrict__ endp,
                         const int* __restrict__ ssrc,
                         const float* __restrict__ consts,
                         const float* __restrict__ W1, const float* __restrict__ b1,
                         const float* __restrict__ W2,
                         const float* __restrict__ as2, const float* __restrict__ ad2,
                         float* __restrict__ h2,
                         float* __restrict__ als2, float* __restrict__ ald2, int N) {
    int n = blockIdx.x * blockDim.x + threadIdx.x;
    if (n >= N) return;
    float S[4], D[4];
    #pragma unroll
    for (int h = 0; h < 4; ++h) { S[h] = consts[h]; D[h] = consts[4 + h]; }
    float xn = x[n];
    float s1[4], t1[4];
    // self-loop term (src = dst = n)
    #pragma unroll
    for (int h = 0; h < 4; ++h) {
        float v = xn * (S[h] + D[h]);
        v = (v > 0.f) ? v : NEG_SLOPE * v;
        float w = __expf(v);
        s1[h] = w; t1[h] = w * xn;
    }
    int b = off[n], e = endp[n];
    for (int i = b; i < e; ++i) {
        float xs = x[ssrc[i]];
        #pragma unroll
        for (int h = 0; h < 4; ++h) {
            float v = xs * S[h] + xn * D[h];
            v = (v > 0.f) ? v : NEG_SLOPE * v;
            float w = __expf(v);
            s1[h] += w; t1[h] += w * xs;
        }
    }
    float tt[4];
    #pragma unroll
    for (int h = 0; h < 4; ++h) tt[h] = t1[h] / s1[h];
    float o[8];
    #pragma unroll
    for (int c = 0; c < 8; ++c) o[c] = 0.f;
    #pragma unroll
    for (int h = 0; h < 4; ++h) {
        #pragma unroll
        for (int c = 0; c < 8; ++c) {
            float r = fmaxf(tt[h] * W1[h * 8 + c] + b1[h * 8 + c], 0.f);
            #pragma unroll
            for (int c2 = 0; c2 < 8; ++c2) o[c2] += r * W2[(h * 8 + c) * 8 + c2];
        }
    }
    float as = 0.f, ad = 0.f;
    #pragma unroll
    for (int c = 0; c < 8; ++c) { as += o[c] * as2[c]; ad += o[c] * ad2[c]; }
    float4* hv = (float4*)&h2[(size_t)n * 8];
    hv[0] = make_float4(o[0], o[1], o[2], o[3]);
    hv[1] = make_float4(o[4], o[5], o[6], o[7]);
    als2[n] = as;
    ald2[n] = ad;
}

// Layer 2 aggregation + output epilogue.
__global__ void l2_fused(const int* __restrict__ off, const int* __restrict__ endp,
                         const int* __restrict__ ssrc,
                         const float* __restrict__ als2, const float* __restrict__ ald2,
                         const float* __restrict__ h2,
                         const float* __restrict__ b2,
                         float* __restrict__ out, int N) {
    int n = blockIdx.x * blockDim.x + threadIdx.x;
    if (n >= N) return;
    float aldn = ald2[n];
    // self-loop term
    float v = als2[n] + aldn;
    v = (v > 0.f) ? v : NEG_SLOPE * v;
    float w = __expf(v);
    float s2 = w;
    const float4* hv = (const float4*)&h2[(size_t)n * 8];
    float4 a = hv[0], bq = hv[1];
    float acc[8] = { w * a.x, w * a.y, w * a.z, w * a.w,
                     w * bq.x, w * bq.y, w * bq.z, w * bq.w };
    int b = off[n], e = endp[n];
    for (int i = b; i < e; ++i) {
        int sr = ssrc[i];
        float vv = als2[sr] + aldn;
        vv = (vv > 0.f) ? vv : NEG_SLOPE * vv;
        float ww = __expf(vv);
        s2 += ww;
        const float4* hs = (const float4*)&h2[(size_t)sr * 8];
        float4 ha = hs[0], hb = hs[1];
        acc[0] += ww * ha.x; acc[1] += ww * ha.y;
        acc[2] += ww * ha.z; acc[3] += ww * ha.w;
        acc[4] += ww * hb.x; acc[5] += ww * hb.y;
        acc[6] += ww * hb.z; acc[7] += ww * hb.w;
    }
    float inv = 1.f / s2;
    float4* ov = (float4*)&out[(size_t)n * 8];
    ov[0] = make_float4(acc[0] * inv + b2[0], acc[1] * inv + b2[1],
                        acc[2] * inv + b2[2], acc[3] * inv + b2[3]);
    ov[1] = make_float4(acc[4] * inv + b2[4], acc[5] * inv + b2[5],
                        acc[6] * inv + b2[6], acc[7] * inv + b2[7]);
}

// ---------------- fallback path (R2, atomic-based; known-correct) ----------------

__global__ void edge_pass1(const int* __restrict__ ei, const float* __restrict__ x,
                           const float* __restrict__ consts,
                           float* __restrict__ s1, float* __restrict__ t1, int E, int N) {
    int e = blockIdx.x * blockDim.x + threadIdx.x;
    if (e >= E + N) return;
    int src, dst;
    if (e < E) { src = ei[e]; dst = ei[E + e]; }
    else       { src = dst = e - E; }
    float xs = x[src], xd = x[dst];
    #pragma unroll
    for (int h = 0; h < 4; ++h) {
        float v = xs * consts[h] + xd * consts[4 + h];
        v = (v > 0.f) ? v : NEG_SLOPE * v;
        float w = __expf(v);
        atomicAdd(&s1[dst * 4 + h], w);
        atomicAdd(&t1[dst * 4 + h], w * xs);
    }
}

__global__ void node_mid(const float* __restrict__ s1, const float* __restrict__ t1,
                         const float* __restrict__ W1, const float* __restrict__ b1,
                         const float* __restrict__ W2,
                         const float* __restrict__ as2, const float* __restrict__ ad2,
                         float* __restrict__ h2, float* __restrict__ als2,
                         float* __restrict__ ald2, int N) {
    int n = blockIdx.x * blockDim.x + threadIdx.x;
    if (n >= N) return;
    float o[8];
    #pragma unroll
    for (int c = 0; c < 8; ++c) o[c] = 0.f;
    #pragma unroll
    for (int h = 0; h < 4; ++h) {
        float t = t1[n * 4 + h] / s1[n * 4 + h];
        #pragma unroll
        for (int c = 0; c < 8; ++c) {
            float r = fmaxf(t * W1[h * 8 + c] + b1[h * 8 + c], 0.f);
            #pragma unroll
            for (int c2 = 0; c2 < 8; ++c2) o[c2] += r * W2[(h * 8 + c) * 8 + c2];
        }
    }
    float as = 0.f, ad = 0.f;
    #pragma unroll
    for (int c = 0; c < 8; ++c) { h2[n * 8 + c] = o[c]; as += o[c] * as2[c]; ad += o[c] * ad2[c]; }
    als2[n] = as; ald2[n] = ad;
}

__global__ void edge_pass2(const int* __restrict__ ei, const float* __restrict__ als2,
                           const float* __restrict__ ald2, const float* __restrict__ h2,
                           float* __restrict__ s2, float* __restrict__ acc2, int E, int N) {
    int e = blockIdx.x * blockDim.x + threadIdx.x;
    if (e >= E + N) return;
    int src, dst;
    if (e < E) { src = ei[e]; dst = ei[E + e]; }
    else       { src = dst = e - E; }
    float v = als2[src] + ald2[dst];
    v = (v > 0.f) ? v : NEG_SLOPE * v;
    float w = __expf(v);
    atomicAdd(&s2[dst], w);
    const float4* hs = (const float4*)&h2[src * 8];
    float4 a = hs[0], bq = hs[1];
    float* acc = &acc2[dst * 8];
    atomicAdd(&acc[0], w * a.x);  atomicAdd(&acc[1], w * a.y);
    atomicAdd(&acc[2], w * a.z);  atomicAdd(&acc[3], w * a.w);
    atomicAdd(&acc[4], w * bq.x); atomicAdd(&acc[5], w * bq.y);
    atomicAdd(&acc[6], w * bq.z); atomicAdd(&acc[7], w * bq.w);
}

__global__ void node_out(const float* __restrict__ s2, const float* __restrict__ acc2,
                         const float* __restrict__ b2, float* __restrict__ out, int N) {
    int i = blockIdx.x * blockDim.x + threadIdx.x;
    if (i >= N * 8) return;
    out[i] = acc2[i] / s2[i >> 3] + b2[i & 7];
}

// ---------------------------------------------------------------------------

extern "C" void kernel_launch(void* const* d_in, const int* in_sizes, int n_in,
                              void* d_out, int out_size, void* d_ws, size_t ws_size,
                              hipStream_t stream) {
    const float* x   = (const float*)d_in[0];
    const int*   ei  = (const int*)d_in[1];
    const float* W1  = (const float*)d_in[2];
    const float* as1 = (const float*)d_in[3];
    const float* ad1 = (const float*)d_in[4];
    const float* b1  = (const float*)d_in[5];
    const float* W2  = (const float*)d_in[6];
    const float* as2 = (const float*)d_in[7];
    const float* ad2 = (const float*)d_in[8];
    const float* b2  = (const float*)d_in[9];
    float* out = (float*)d_out;

    const int N = in_sizes[0];          // 100000
    const int E = in_sizes[1] / 2;      // 3200000
    const int nb = (N + 255) / 256;

    float* ws = (float*)d_ws;
    size_t need = (size_t)(16 + 12 * (size_t)N + 1024 + (size_t)E) * sizeof(float);

    if (ws_size >= need && nb <= 512) {
        // ---- CSR pull path ----
        float* consts = ws;                              // 16
        int*   off    = (int*)(ws + 16);                 // N
        int*   cursor = off + N;                         // N
        float* als2   = (float*)(cursor + N);            // N
        float* ald2   = als2 + N;                        // N
        float* h2     = ald2 + N;                        // 8N
        int*   deg    = (int*)h2;                        // alias (pre-l1_fused only)
        int*   partial= (int*)(h2 + 8 * (size_t)N);      // 1024
        int*   ssrc   = partial + 1024;                  // E

        hipMemsetAsync(deg, 0, (size_t)N * sizeof(int), stream);
        prep_consts<<<1, 64, 0, stream>>>(W1, as1, ad1, consts);
        hist_kernel<<<(E + 255) / 256, 256, 0, stream>>>(ei, deg, E);
        scan_block_sums<<<nb, 256, 0, stream>>>(deg, partial, N);
        scan_partials<<<1, 512, 0, stream>>>(partial, nb);
        scan_apply<<<nb, 256, 0, stream>>>(deg, partial, off, cursor, N);
        scatter_edges<<<(E + 255) / 256, 256, 0, stream>>>(ei, cursor, ssrc, E);
        l1_fused<<<nb, 256, 0, stream>>>(x, off, cursor, ssrc, consts,
                                         W1, b1, W2, as2, ad2, h2, als2, ald2, N);
        l2_fused<<<nb, 256, 0, stream>>>(off, cursor, ssrc, als2, ald2, h2, b2, out, N);
    } else {
        // ---- fallback: R2 atomic path (10.8 MB ws) ----
        float* consts = ws;
        float* s1   = ws + 16;
        float* t1   = s1 + 4 * (size_t)N;
        float* h2   = t1 + 4 * (size_t)N;
        float* als2 = h2 + 8 * (size_t)N;
        float* ald2 = als2 + (size_t)N;
        float* s2   = ald2 + (size_t)N;
        float* acc2 = s2 + (size_t)N;

        hipMemsetAsync(ws, 0, (16 + 8 * (size_t)N) * sizeof(float), stream);
        hipMemsetAsync(s2, 0, 9 * (size_t)N * sizeof(float), stream);
        prep_consts<<<1, 64, 0, stream>>>(W1, as1, ad1, consts);
        int total = E + N;
        edge_pass1<<<(total + 255) / 256, 256, 0, stream>>>(ei, x, consts, s1, t1, E, N);
        node_mid<<<nb, 256, 0, stream>>>(s1, t1, W1, b1, W2, as2, ad2, h2, als2, ald2, N);
        edge_pass2<<<(total + 255) / 256, 256, 0, stream>>>(ei, als2, ald2, h2, s2, acc2, E, N);
        node_out<<<(N * 8 + 255) / 256, 256, 0, stream>>>(s2, acc2, b2, out, N);
    }
}

// Round 4
// 514.937 us; speedup vs baseline: 5.4859x; 1.1763x over previous
//
#include <hip/hip_runtime.h>
#include <hip/hip_bf16.h>

#define NEG_SLOPE 0.2f

// ---------------------------------------------------------------------------
// GAT 2-layer, N=100k, E=3.2M (+self-loops handled analytically per node).
//
// R4: coarse-bucket edges by dst (256 nodes/bucket -> NB=391 buckets), then
// per-bucket aggregation with LDS float atomics. Eliminates R3's 6.4M global
// atomics (32B RMW each) and the random 4B scatter (194MB write amplification).
//   - bucket_hist:  LDS hist, 131K flush atomics
//   - scan_init:    1-block scan of 512 counts
//   - bucket_scatter: per-(block,bucket) reserve atomic (~100K), packed 4B
//                     records (src | local_dst<<17), dense ~128B runs
//   - l1_bucket:    per-bucket LDS s1/t1 (stride 9 -> no 16-way bank conflict),
//                   fused layer-1 epilogue + W2 transform + layer-2 logits
//   - l2_bucket:    per-bucket LDS s2/acc (stride 9), fused output epilogue
//
// Layer 1 collapses because IN==1 (h1 = x*W1 is rank-1):
//   logit_src[n,h]=x[n]*S1[h], logit_dst[n,h]=x[n]*D1[h],
//   out1[n,h,c]=W1[h,c]*t1[n,h]+b1. No softmax max-subtraction needed
//   (|logit| <~ 30, exp safe in fp32; verified R2/R3 absmax 9.8e-4).
//
// ws layout (4B units):
//   [0..15]      consts S1[4],D1[4]
//   [16..527]    gcnt[512]    (zeroed)
//   [528..1039]  gbase[512]
//   [1040..1551] gcursor[512]
//   [+N]         als2
//   [+N]         ald2
//   [+8N]        h2
//   [+E]         pairs (packed)
// total = 1552 + 10N + E units (~16.9MB @ N=100k,E=3.2M; R3 proved >=17.6MB).
// Guards: N <= 131072 (17-bit src, NB<=512). Fallback: R2 atomic path.
// ---------------------------------------------------------------------------

__global__ void prep_consts(const float* __restrict__ W1,
                            const float* __restrict__ as1,
                            const float* __restrict__ ad1,
                            float* __restrict__ consts) {
    int t = threadIdx.x;
    if (t >= 8) return;
    int h = t & 3;
    const float* a = (t < 4) ? as1 : ad1;
    float s = 0.f;
    #pragma unroll
    for (int c = 0; c < 8; ++c)
        s += W1[h * 8 + c] * a[h * 8 + c];
    consts[t] = s;
}

__global__ void bucket_hist(const int* __restrict__ ei, int* __restrict__ gcnt, int E) {
    __shared__ int cnt[512];
    int t = threadIdx.x;
    cnt[t] = 0; cnt[t + 256] = 0;
    __syncthreads();
    int stride = gridDim.x * 256;
    for (int e = blockIdx.x * 256 + t; e < E; e += stride)
        atomicAdd(&cnt[ei[E + e] >> 8], 1);
    __syncthreads();
    for (int i = t; i < 512; i += 256) {
        int c = cnt[i];
        if (c) atomicAdd(&gcnt[i], c);
    }
}

// single block, 512 threads: exclusive scan of bucket counts
__global__ void scan_init(const int* __restrict__ gcnt,
                          int* __restrict__ gbase, int* __restrict__ gcursor) {
    __shared__ int buf[512];
    int t = threadIdx.x;
    int orig = gcnt[t];
    buf[t] = orig;
    __syncthreads();
    for (int o = 1; o < 512; o <<= 1) {
        int add = (t >= o) ? buf[t - o] : 0;
        __syncthreads();
        buf[t] += add;
        __syncthreads();
    }
    int base = buf[t] - orig;
    gbase[t] = base;
    gcursor[t] = base;
}

__global__ void bucket_scatter(const int* __restrict__ ei, int* __restrict__ gcursor,
                               unsigned int* __restrict__ pairs, int E) {
    __shared__ int cnt[512];
    __shared__ int basel[512];
    int t = threadIdx.x;
    int chunk = (E + gridDim.x - 1) / gridDim.x;
    int lo = blockIdx.x * chunk;
    int hi = min(E, lo + chunk);
    cnt[t] = 0; cnt[t + 256] = 0;
    __syncthreads();
    for (int e = lo + t; e < hi; e += 256)
        atomicAdd(&cnt[ei[E + e] >> 8], 1);
    __syncthreads();
    for (int i = t; i < 512; i += 256) {
        int c = cnt[i];
        basel[i] = c ? atomicAdd(&gcursor[i], c) : 0;
        cnt[i] = 0;
    }
    __syncthreads();
    for (int e = lo + t; e < hi; e += 256) {
        int s = ei[e];
        int d = ei[E + e];               // L2-hit: just read in phase 1
        int bk = d >> 8;
        int loc = atomicAdd(&cnt[bk], 1);
        pairs[basel[bk] + loc] = (unsigned)s | ((unsigned)(d & 255) << 17);
    }
}

// Layer-1 aggregation + epilogue + W2 transform + layer-2 logits, per bucket.
__global__ void l1_bucket(const float* __restrict__ x,
                          const int* __restrict__ gbase, const int* __restrict__ gcnt,
                          const unsigned int* __restrict__ pairs,
                          const float* __restrict__ consts,
                          const float* __restrict__ W1, const float* __restrict__ b1,
                          const float* __restrict__ W2,
                          const float* __restrict__ as2, const float* __restrict__ ad2,
                          float* __restrict__ h2, float* __restrict__ als2,
                          float* __restrict__ ald2, int N) {
    __shared__ float st[256 * 9];   // row ld: [0..3]=s1[h], [4..7]=t1[h] (stride 9)
    __shared__ float xl[256];
    int t = threadIdx.x;
    int bk = blockIdx.x;
    int nb0 = bk << 8;
    int nn = min(256, N - nb0);
    #pragma unroll
    for (int j = 0; j < 9; ++j) st[t * 9 + j] = 0.f;
    if (t < nn) xl[t] = x[nb0 + t];
    float S[4], D[4];
    #pragma unroll
    for (int h = 0; h < 4; ++h) { S[h] = consts[h]; D[h] = consts[4 + h]; }
    __syncthreads();
    int b = gbase[bk];
    int hi = b + gcnt[bk];
    for (int i = b + t; i < hi; i += 256) {
        unsigned p = pairs[i];
        int src = p & 131071;
        int ld = p >> 17;
        float xs = x[src];
        float xd = xl[ld];
        float* row = &st[ld * 9];
        #pragma unroll
        for (int h = 0; h < 4; ++h) {
            float v = xs * S[h] + xd * D[h];
            v = (v > 0.f) ? v : NEG_SLOPE * v;
            float w = __expf(v);
            atomicAdd(&row[h], w);
            atomicAdd(&row[4 + h], w * xs);
        }
    }
    __syncthreads();
    if (t < nn) {
        int n = nb0 + t;
        float xn = xl[t];
        float o[8];
        #pragma unroll
        for (int c = 0; c < 8; ++c) o[c] = 0.f;
        #pragma unroll
        for (int h = 0; h < 4; ++h) {
            float v = xn * (S[h] + D[h]);           // self-loop term
            v = (v > 0.f) ? v : NEG_SLOPE * v;
            float w = __expf(v);
            float s1 = st[t * 9 + h] + w;
            float tt = (st[t * 9 + 4 + h] + w * xn) / s1;
            #pragma unroll
            for (int c = 0; c < 8; ++c) {
                float r = fmaxf(tt * W1[h * 8 + c] + b1[h * 8 + c], 0.f);
                #pragma unroll
                for (int c2 = 0; c2 < 8; ++c2) o[c2] += r * W2[(h * 8 + c) * 8 + c2];
            }
        }
        float as = 0.f, ad = 0.f;
        #pragma unroll
        for (int c = 0; c < 8; ++c) { as += o[c] * as2[c]; ad += o[c] * ad2[c]; }
        float4* hv = (float4*)&h2[(size_t)n * 8];
        hv[0] = make_float4(o[0], o[1], o[2], o[3]);
        hv[1] = make_float4(o[4], o[5], o[6], o[7]);
        als2[n] = as;
        ald2[n] = ad;
    }
}

// Layer-2 aggregation + output epilogue, per bucket.
__global__ void l2_bucket(const int* __restrict__ gbase, const int* __restrict__ gcnt,
                          const unsigned int* __restrict__ pairs,
                          const float* __restrict__ als2, const float* __restrict__ ald2,
                          const float* __restrict__ h2, const float* __restrict__ b2,
                          float* __restrict__ out, int N) {
    __shared__ float sa[256 * 9];   // row ld: [0]=s2, [1..8]=acc (stride 9)
    __shared__ float all[256], adl[256];
    int t = threadIdx.x;
    int bk = blockIdx.x;
    int nb0 = bk << 8;
    int nn = min(256, N - nb0);
    #pragma unroll
    for (int j = 0; j < 9; ++j) sa[t * 9 + j] = 0.f;
    if (t < nn) { all[t] = als2[nb0 + t]; adl[t] = ald2[nb0 + t]; }
    __syncthreads();
    int b = gbase[bk];
    int hi = b + gcnt[bk];
    for (int i = b + t; i < hi; i += 256) {
        unsigned p = pairs[i];
        int src = p & 131071;
        int ld = p >> 17;
        float v = als2[src] + adl[ld];
        v = (v > 0.f) ? v : NEG_SLOPE * v;
        float w = __expf(v);
        const float4* hv = (const float4*)&h2[(size_t)src * 8];
        float4 ha = hv[0], hb = hv[1];
        float* row = &sa[ld * 9];
        atomicAdd(&row[0], w);
        atomicAdd(&row[1], w * ha.x); atomicAdd(&row[2], w * ha.y);
        atomicAdd(&row[3], w * ha.z); atomicAdd(&row[4], w * ha.w);
        atomicAdd(&row[5], w * hb.x); atomicAdd(&row[6], w * hb.y);
        atomicAdd(&row[7], w * hb.z); atomicAdd(&row[8], w * hb.w);
    }
    __syncthreads();
    if (t < nn) {
        int n = nb0 + t;
        float v = all[t] + adl[t];               // self-loop
        v = (v > 0.f) ? v : NEG_SLOPE * v;
        float w = __expf(v);
        const float4* hv = (const float4*)&h2[(size_t)n * 8];
        float4 ha = hv[0], hb = hv[1];
        float s2 = sa[t * 9] + w;
        float inv = 1.f / s2;
        float4* ov = (float4*)&out[(size_t)n * 8];
        ov[0] = make_float4((sa[t * 9 + 1] + w * ha.x) * inv + b2[0],
                            (sa[t * 9 + 2] + w * ha.y) * inv + b2[1],
                            (sa[t * 9 + 3] + w * ha.z) * inv + b2[2],
                            (sa[t * 9 + 4] + w * ha.w) * inv + b2[3]);
        ov[1] = make_float4((sa[t * 9 + 5] + w * hb.x) * inv + b2[4],
                            (sa[t * 9 + 6] + w * hb.y) * inv + b2[5],
                            (sa[t * 9 + 7] + w * hb.z) * inv + b2[6],
                            (sa[t * 9 + 8] + w * hb.w) * inv + b2[7]);
    }
}

// ---------------- fallback path (R2, atomic-based; known-correct) ----------------

__global__ void edge_pass1(const int* __restrict__ ei, const float* __restrict__ x,
                           const float* __restrict__ consts,
                           float* __restrict__ s1, float* __restrict__ t1, int E, int N) {
    int e = blockIdx.x * blockDim.x + threadIdx.x;
    if (e >= E + N) return;
    int src, dst;
    if (e < E) { src = ei[e]; dst = ei[E + e]; }
    else       { src = dst = e - E; }
    float xs = x[src], xd = x[dst];
    #pragma unroll
    for (int h = 0; h < 4; ++h) {
        float v = xs * consts[h] + xd * consts[4 + h];
        v = (v > 0.f) ? v : NEG_SLOPE * v;
        float w = __expf(v);
        atomicAdd(&s1[dst * 4 + h], w);
        atomicAdd(&t1[dst * 4 + h], w * xs);
    }
}

__global__ void node_mid(const float* __restrict__ s1, const float* __restrict__ t1,
                         const float* __restrict__ W1, const float* __restrict__ b1,
                         const float* __restrict__ W2,
                         const float* __restrict__ as2, const float* __restrict__ ad2,
                         float* __restrict__ h2, float* __restrict__ als2,
                         float* __restrict__ ald2, int N) {
    int n = blockIdx.x * blockDim.x + threadIdx.x;
    if (n >= N) return;
    float o[8];
    #pragma unroll
    for (int c = 0; c < 8; ++c) o[c] = 0.f;
    #pragma unroll
    for (int h = 0; h < 4; ++h) {
        float t = t1[n * 4 + h] / s1[n * 4 + h];
        #pragma unroll
        for (int c = 0; c < 8; ++c) {
            float r = fmaxf(t * W1[h * 8 + c] + b1[h * 8 + c], 0.f);
            #pragma unroll
            for (int c2 = 0; c2 < 8; ++c2) o[c2] += r * W2[(h * 8 + c) * 8 + c2];
        }
    }
    float as = 0.f, ad = 0.f;
    #pragma unroll
    for (int c = 0; c < 8; ++c) { h2[n * 8 + c] = o[c]; as += o[c] * as2[c]; ad += o[c] * ad2[c]; }
    als2[n] = as; ald2[n] = ad;
}

__global__ void edge_pass2(const int* __restrict__ ei, const float* __restrict__ als2,
                           const float* __restrict__ ald2, const float* __restrict__ h2,
                           float* __restrict__ s2, float* __restrict__ acc2, int E, int N) {
    int e = blockIdx.x * blockDim.x + threadIdx.x;
    if (e >= E + N) return;
    int src, dst;
    if (e < E) { src = ei[e]; dst = ei[E + e]; }
    else       { src = dst = e - E; }
    float v = als2[src] + ald2[dst];
    v = (v > 0.f) ? v : NEG_SLOPE * v;
    float w = __expf(v);
    atomicAdd(&s2[dst], w);
    const float4* hs = (const float4*)&h2[src * 8];
    float4 a = hs[0], bq = hs[1];
    float* acc = &acc2[dst * 8];
    atomicAdd(&acc[0], w * a.x);  atomicAdd(&acc[1], w * a.y);
    atomicAdd(&acc[2], w * a.z);  atomicAdd(&acc[3], w * a.w);
    atomicAdd(&acc[4], w * bq.x); atomicAdd(&acc[5], w * bq.y);
    atomicAdd(&acc[6], w * bq.z); atomicAdd(&acc[7], w * bq.w);
}

__global__ void node_out(const float* __restrict__ s2, const float* __restrict__ acc2,
                         const float* __restrict__ b2, float* __restrict__ out, int N) {
    int i = blockIdx.x * blockDim.x + threadIdx.x;
    if (i >= N * 8) return;
    out[i] = acc2[i] / s2[i >> 3] + b2[i & 7];
}

// ---------------------------------------------------------------------------

extern "C" void kernel_launch(void* const* d_in, const int* in_sizes, int n_in,
                              void* d_out, int out_size, void* d_ws, size_t ws_size,
                              hipStream_t stream) {
    const float* x   = (const float*)d_in[0];
    const int*   ei  = (const int*)d_in[1];
    const float* W1  = (const float*)d_in[2];
    const float* as1 = (const float*)d_in[3];
    const float* ad1 = (const float*)d_in[4];
    const float* b1  = (const float*)d_in[5];
    const float* W2  = (const float*)d_in[6];
    const float* as2 = (const float*)d_in[7];
    const float* ad2 = (const float*)d_in[8];
    const float* b2  = (const float*)d_in[9];
    float* out = (float*)d_out;

    const int N = in_sizes[0];          // 100000
    const int E = in_sizes[1] / 2;      // 3200000
    const int NB = (N + 255) >> 8;      // 391 buckets of 256 nodes

    float* ws = (float*)d_ws;
    size_t need = (size_t)(1552 + 10 * (size_t)N + (size_t)E) * sizeof(float);

    if (N <= 131072 && ws_size >= need) {
        float*    consts  = ws;                         // 16
        int*      gcnt    = (int*)(ws + 16);            // 512
        int*      gbase   = gcnt + 512;                 // 512
        int*      gcursor = gbase + 512;                // 512
        float*    als2    = ws + 1552;                  // N
        float*    ald2    = als2 + N;                   // N
        float*    h2      = ald2 + N;                   // 8N
        unsigned* pairs   = (unsigned*)(h2 + 8 * (size_t)N);  // E

        hipMemsetAsync(gcnt, 0, 512 * sizeof(int), stream);
        prep_consts<<<1, 64, 0, stream>>>(W1, as1, ad1, consts);
        bucket_hist<<<256, 256, 0, stream>>>(ei, gcnt, E);
        scan_init<<<1, 512, 0, stream>>>(gcnt, gbase, gcursor);
        bucket_scatter<<<256, 256, 0, stream>>>(ei, gcursor, pairs, E);
        l1_bucket<<<NB, 256, 0, stream>>>(x, gbase, gcnt, pairs, consts,
                                          W1, b1, W2, as2, ad2, h2, als2, ald2, N);
        l2_bucket<<<NB, 256, 0, stream>>>(gbase, gcnt, pairs, als2, ald2, h2, b2, out, N);
    } else {
        // fallback: R2 atomic path (10.8 MB ws, known-correct)
        float* consts = ws;
        float* s1   = ws + 16;
        float* t1   = s1 + 4 * (size_t)N;
        float* h2   = t1 + 4 * (size_t)N;
        float* als2 = h2 + 8 * (size_t)N;
        float* ald2 = als2 + (size_t)N;
        float* s2   = ald2 + (size_t)N;
        float* acc2 = s2 + (size_t)N;

        hipMemsetAsync(ws, 0, (16 + 8 * (size_t)N) * sizeof(float), stream);
        hipMemsetAsync(s2, 0, 9 * (size_t)N * sizeof(float), stream);
        prep_consts<<<1, 64, 0, stream>>>(W1, as1, ad1, consts);
        int total = E + N;
        edge_pass1<<<(total + 255) / 256, 256, 0, stream>>>(ei, x, consts, s1, t1, E, N);
        node_mid<<<(N + 255) / 256, 256, 0, stream>>>(s1, t1, W1, b1, W2, as2, ad2, h2, als2, ald2, N);
        edge_pass2<<<(total + 255) / 256, 256, 0, stream>>>(ei, als2, ald2, h2, s2, acc2, E, N);
        node_out<<<(N * 8 + 255) / 256, 256, 0, stream>>>(s2, acc2, b2, out, N);
    }
}

// Round 5
// 471.294 us; speedup vs baseline: 5.9939x; 1.0926x over previous
//
#include <hip/hip_runtime.h>
#include <hip/hip_bf16.h>

#define NEG_SLOPE 0.2f

// ---------------------------------------------------------------------------
// GAT 2-layer, N=100k, E=3.2M (+self-loops handled analytically per node).
//
// R5: R4's coarse bucket sort (256 nodes/bucket, dense scatter) kept, but the
// aggregation kernels now run 4 "window" blocks per bucket (64 nodes each,
// private 64x9 LDS accumulator, exclusive ownership -> no merge). Fixes R4's
// l2_bucket latency starvation (391 blocks -> 12.8% occupancy, VALUBusy 1%):
// 1564 blocks give ~4x wave-level latency hiding; pairs re-read 4x is ~8us BW.
// hist/scatter grids 256 -> 512 for the same occupancy reason.
//
// Layer 1 collapses because IN==1 (h1 = x*W1 is rank-1):
//   logit_src[n,h]=x[n]*S1[h], logit_dst[n,h]=x[n]*D1[h],
//   out1[n,h,c]=W1[h,c]*t1[n,h]+b1. No softmax max-subtraction needed
//   (|logit| <~ 30, exp safe in fp32; verified R2-R4 absmax 9.8e-4).
//
// ws layout (4B units):
//   [0..15]      consts S1[4],D1[4]
//   [16..527]    gcnt[512]    (zeroed)
//   [528..1039]  gbase[512]
//   [1040..1551] gcursor[512]
//   [+N]         als2
//   [+N]         ald2
//   [+8N]        h2
//   [+E]         pairs (packed src | local_dst<<17)
// total = 1552 + 10N + E units (~16.9MB; R3 proved ws >= 17.6MB works).
// Guards: N <= 131072 (17-bit src, <=512 buckets). Fallback: R2 atomic path.
// ---------------------------------------------------------------------------

__global__ void prep_consts(const float* __restrict__ W1,
                            const float* __restrict__ as1,
                            const float* __restrict__ ad1,
                            float* __restrict__ consts) {
    int t = threadIdx.x;
    if (t >= 8) return;
    int h = t & 3;
    const float* a = (t < 4) ? as1 : ad1;
    float s = 0.f;
    #pragma unroll
    for (int c = 0; c < 8; ++c)
        s += W1[h * 8 + c] * a[h * 8 + c];
    consts[t] = s;
}

__global__ void bucket_hist(const int* __restrict__ ei, int* __restrict__ gcnt, int E) {
    __shared__ int cnt[512];
    int t = threadIdx.x;
    cnt[t] = 0; cnt[t + 256] = 0;
    __syncthreads();
    int stride = gridDim.x * 256;
    for (int e = blockIdx.x * 256 + t; e < E; e += stride)
        atomicAdd(&cnt[ei[E + e] >> 8], 1);
    __syncthreads();
    for (int i = t; i < 512; i += 256) {
        int c = cnt[i];
        if (c) atomicAdd(&gcnt[i], c);
    }
}

// single block, 512 threads: exclusive scan of bucket counts
__global__ void scan_init(const int* __restrict__ gcnt,
                          int* __restrict__ gbase, int* __restrict__ gcursor) {
    __shared__ int buf[512];
    int t = threadIdx.x;
    int orig = gcnt[t];
    buf[t] = orig;
    __syncthreads();
    for (int o = 1; o < 512; o <<= 1) {
        int add = (t >= o) ? buf[t - o] : 0;
        __syncthreads();
        buf[t] += add;
        __syncthreads();
    }
    int base = buf[t] - orig;
    gbase[t] = base;
    gcursor[t] = base;
}

__global__ void bucket_scatter(const int* __restrict__ ei, int* __restrict__ gcursor,
                               unsigned int* __restrict__ pairs, int E) {
    __shared__ int cnt[512];
    __shared__ int basel[512];
    int t = threadIdx.x;
    int chunk = (E + gridDim.x - 1) / gridDim.x;
    int lo = blockIdx.x * chunk;
    int hi = min(E, lo + chunk);
    cnt[t] = 0; cnt[t + 256] = 0;
    __syncthreads();
    for (int e = lo + t; e < hi; e += 256)
        atomicAdd(&cnt[ei[E + e] >> 8], 1);
    __syncthreads();
    for (int i = t; i < 512; i += 256) {
        int c = cnt[i];
        basel[i] = c ? atomicAdd(&gcursor[i], c) : 0;
        cnt[i] = 0;
    }
    __syncthreads();
    for (int e = lo + t; e < hi; e += 256) {
        int s = ei[e];
        int d = ei[E + e];
        int bk = d >> 8;
        int loc = atomicAdd(&cnt[bk], 1);
        pairs[basel[bk] + loc] = (unsigned)s | ((unsigned)(d & 255) << 17);
    }
}

// Layer-1 aggregation + epilogue + W2 transform + layer-2 logits.
// One block per (bucket, 64-node window): blockIdx = bk*4 + w.
__global__ void l1_win(const float* __restrict__ x,
                       const int* __restrict__ gbase, const int* __restrict__ gcnt,
                       const unsigned int* __restrict__ pairs,
                       const float* __restrict__ consts,
                       const float* __restrict__ W1, const float* __restrict__ b1,
                       const float* __restrict__ W2,
                       const float* __restrict__ as2, const float* __restrict__ ad2,
                       float* __restrict__ h2, float* __restrict__ als2,
                       float* __restrict__ ald2, int N) {
    __shared__ float st[64 * 9];   // window rows: [0..3]=s1[h], [4..7]=t1[h]
    __shared__ float xl[64];
    int t = threadIdx.x;
    int bk = blockIdx.x >> 2;
    int w  = blockIdx.x & 3;
    int node0 = (bk << 8) + (w << 6);
    int nw = min(64, N - node0);           // may be <= 0 (empty window)
    if (t < 64) {
        #pragma unroll
        for (int j = 0; j < 9; ++j) st[t * 9 + j] = 0.f;
        if (t < nw) xl[t] = x[node0 + t];
    }
    float S[4], D[4];
    #pragma unroll
    for (int h = 0; h < 4; ++h) { S[h] = consts[h]; D[h] = consts[4 + h]; }
    __syncthreads();
    int b = gbase[bk];
    int hi = b + gcnt[bk];
    for (int i = b + t; i < hi; i += 256) {
        unsigned p = pairs[i];
        int ld = p >> 17;
        if ((ld >> 6) != w) continue;      // not my window
        int src = p & 131071;
        float xs = x[src];
        float xd = xl[ld & 63];
        float* row = &st[(ld & 63) * 9];
        #pragma unroll
        for (int h = 0; h < 4; ++h) {
            float v = xs * S[h] + xd * D[h];
            v = (v > 0.f) ? v : NEG_SLOPE * v;
            float ww = __expf(v);
            atomicAdd(&row[h], ww);
            atomicAdd(&row[4 + h], ww * xs);
        }
    }
    __syncthreads();
    if (t < nw) {
        int n = node0 + t;
        float xn = xl[t];
        float o[8];
        #pragma unroll
        for (int c = 0; c < 8; ++c) o[c] = 0.f;
        #pragma unroll
        for (int h = 0; h < 4; ++h) {
            float v = xn * (S[h] + D[h]);           // self-loop term
            v = (v > 0.f) ? v : NEG_SLOPE * v;
            float ww = __expf(v);
            float s1 = st[t * 9 + h] + ww;
            float tt = (st[t * 9 + 4 + h] + ww * xn) / s1;
            #pragma unroll
            for (int c = 0; c < 8; ++c) {
                float r = fmaxf(tt * W1[h * 8 + c] + b1[h * 8 + c], 0.f);
                #pragma unroll
                for (int c2 = 0; c2 < 8; ++c2) o[c2] += r * W2[(h * 8 + c) * 8 + c2];
            }
        }
        float as = 0.f, ad = 0.f;
        #pragma unroll
        for (int c = 0; c < 8; ++c) { as += o[c] * as2[c]; ad += o[c] * ad2[c]; }
        float4* hv = (float4*)&h2[(size_t)n * 8];
        hv[0] = make_float4(o[0], o[1], o[2], o[3]);
        hv[1] = make_float4(o[4], o[5], o[6], o[7]);
        als2[n] = as;
        ald2[n] = ad;
    }
}

// Layer-2 aggregation + output epilogue, per (bucket, window).
__global__ void l2_win(const int* __restrict__ gbase, const int* __restrict__ gcnt,
                       const unsigned int* __restrict__ pairs,
                       const float* __restrict__ als2, const float* __restrict__ ald2,
                       const float* __restrict__ h2, const float* __restrict__ b2,
                       float* __restrict__ out, int N) {
    __shared__ float sa[64 * 9];   // window rows: [0]=s2, [1..8]=acc
    __shared__ float all[64], adl[64];
    int t = threadIdx.x;
    int bk = blockIdx.x >> 2;
    int w  = blockIdx.x & 3;
    int node0 = (bk << 8) + (w << 6);
    int nw = min(64, N - node0);
    if (t < 64) {
        #pragma unroll
        for (int j = 0; j < 9; ++j) sa[t * 9 + j] = 0.f;
        if (t < nw) { all[t] = als2[node0 + t]; adl[t] = ald2[node0 + t]; }
    }
    __syncthreads();
    int b = gbase[bk];
    int hi = b + gcnt[bk];
    for (int i = b + t; i < hi; i += 256) {
        unsigned p = pairs[i];
        int ld = p >> 17;
        if ((ld >> 6) != w) continue;
        int src = p & 131071;
        float v = als2[src] + adl[ld & 63];
        v = (v > 0.f) ? v : NEG_SLOPE * v;
        float ww = __expf(v);
        const float4* hv = (const float4*)&h2[(size_t)src * 8];
        float4 ha = hv[0], hb = hv[1];
        float* row = &sa[(ld & 63) * 9];
        atomicAdd(&row[0], ww);
        atomicAdd(&row[1], ww * ha.x); atomicAdd(&row[2], ww * ha.y);
        atomicAdd(&row[3], ww * ha.z); atomicAdd(&row[4], ww * ha.w);
        atomicAdd(&row[5], ww * hb.x); atomicAdd(&row[6], ww * hb.y);
        atomicAdd(&row[7], ww * hb.z); atomicAdd(&row[8], ww * hb.w);
    }
    __syncthreads();
    if (t < nw) {
        int n = node0 + t;
        float v = all[t] + adl[t];               // self-loop
        v = (v > 0.f) ? v : NEG_SLOPE * v;
        float ww = __expf(v);
        const float4* hv = (const float4*)&h2[(size_t)n * 8];
        float4 ha = hv[0], hb = hv[1];
        float s2 = sa[t * 9] + ww;
        float inv = 1.f / s2;
        float4* ov = (float4*)&out[(size_t)n * 8];
        ov[0] = make_float4((sa[t * 9 + 1] + ww * ha.x) * inv + b2[0],
                            (sa[t * 9 + 2] + ww * ha.y) * inv + b2[1],
                            (sa[t * 9 + 3] + ww * ha.z) * inv + b2[2],
                            (sa[t * 9 + 4] + ww * ha.w) * inv + b2[3]);
        ov[1] = make_float4((sa[t * 9 + 5] + ww * hb.x) * inv + b2[4],
                            (sa[t * 9 + 6] + ww * hb.y) * inv + b2[5],
                            (sa[t * 9 + 7] + ww * hb.z) * inv + b2[6],
                            (sa[t * 9 + 8] + ww * hb.w) * inv + b2[7]);
    }
}

// ---------------- fallback path (R2, atomic-based; known-correct) ----------------

__global__ void edge_pass1(const int* __restrict__ ei, const float* __restrict__ x,
                           const float* __restrict__ consts,
                           float* __restrict__ s1, float* __restrict__ t1, int E, int N) {
    int e = blockIdx.x * blockDim.x + threadIdx.x;
    if (e >= E + N) return;
    int src, dst;
    if (e < E) { src = ei[e]; dst = ei[E + e]; }
    else       { src = dst = e - E; }
    float xs = x[src], xd = x[dst];
    #pragma unroll
    for (int h = 0; h < 4; ++h) {
        float v = xs * consts[h] + xd * consts[4 + h];
        v = (v > 0.f) ? v : NEG_SLOPE * v;
        float w = __expf(v);
        atomicAdd(&s1[dst * 4 + h], w);
        atomicAdd(&t1[dst * 4 + h], w * xs);
    }
}

__global__ void node_mid(const float* __restrict__ s1, const float* __restrict__ t1,
                         const float* __restrict__ W1, const float* __restrict__ b1,
                         const float* __restrict__ W2,
                         const float* __restrict__ as2, const float* __restrict__ ad2,
                         float* __restrict__ h2, float* __restrict__ als2,
                         float* __restrict__ ald2, int N) {
    int n = blockIdx.x * blockDim.x + threadIdx.x;
    if (n >= N) return;
    float o[8];
    #pragma unroll
    for (int c = 0; c < 8; ++c) o[c] = 0.f;
    #pragma unroll
    for (int h = 0; h < 4; ++h) {
        float t = t1[n * 4 + h] / s1[n * 4 + h];
        #pragma unroll
        for (int c = 0; c < 8; ++c) {
            float r = fmaxf(t * W1[h * 8 + c] + b1[h * 8 + c], 0.f);
            #pragma unroll
            for (int c2 = 0; c2 < 8; ++c2) o[c2] += r * W2[(h * 8 + c) * 8 + c2];
        }
    }
    float as = 0.f, ad = 0.f;
    #pragma unroll
    for (int c = 0; c < 8; ++c) { h2[n * 8 + c] = o[c]; as += o[c] * as2[c]; ad += o[c] * ad2[c]; }
    als2[n] = as; ald2[n] = ad;
}

__global__ void edge_pass2(const int* __restrict__ ei, const float* __restrict__ als2,
                           const float* __restrict__ ald2, const float* __restrict__ h2,
                           float* __restrict__ s2, float* __restrict__ acc2, int E, int N) {
    int e = blockIdx.x * blockDim.x + threadIdx.x;
    if (e >= E + N) return;
    int src, dst;
    if (e < E) { src = ei[e]; dst = ei[E + e]; }
    else       { src = dst = e - E; }
    float v = als2[src] + ald2[dst];
    v = (v > 0.f) ? v : NEG_SLOPE * v;
    float w = __expf(v);
    atomicAdd(&s2[dst], w);
    const float4* hs = (const float4*)&h2[src * 8];
    float4 a = hs[0], bq = hs[1];
    float* acc = &acc2[dst * 8];
    atomicAdd(&acc[0], w * a.x);  atomicAdd(&acc[1], w * a.y);
    atomicAdd(&acc[2], w * a.z);  atomicAdd(&acc[3], w * a.w);
    atomicAdd(&acc[4], w * bq.x); atomicAdd(&acc[5], w * bq.y);
    atomicAdd(&acc[6], w * bq.z); atomicAdd(&acc[7], w * bq.w);
}

__global__ void node_out(const float* __restrict__ s2, const float* __restrict__ acc2,
                         const float* __restrict__ b2, float* __restrict__ out, int N) {
    int i = blockIdx.x * blockDim.x + threadIdx.x;
    if (i >= N * 8) return;
    out[i] = acc2[i] / s2[i >> 3] + b2[i & 7];
}

// ---------------------------------------------------------------------------

extern "C" void kernel_launch(void* const* d_in, const int* in_sizes, int n_in,
                              void* d_out, int out_size, void* d_ws, size_t ws_size,
                              hipStream_t stream) {
    const float* x   = (const float*)d_in[0];
    const int*   ei  = (const int*)d_in[1];
    const float* W1  = (const float*)d_in[2];
    const float* as1 = (const float*)d_in[3];
    const float* ad1 = (const float*)d_in[4];
    const float* b1  = (const float*)d_in[5];
    const float* W2  = (const float*)d_in[6];
    const float* as2 = (const float*)d_in[7];
    const float* ad2 = (const float*)d_in[8];
    const float* b2  = (const float*)d_in[9];
    float* out = (float*)d_out;

    const int N = in_sizes[0];          // 100000
    const int E = in_sizes[1] / 2;      // 3200000
    const int NB = (N + 255) >> 8;      // 391 buckets of 256 nodes

    float* ws = (float*)d_ws;
    size_t need = (size_t)(1552 + 10 * (size_t)N + (size_t)E) * sizeof(float);

    if (N <= 131072 && ws_size >= need) {
        float*    consts  = ws;                         // 16
        int*      gcnt    = (int*)(ws + 16);            // 512
        int*      gbase   = gcnt + 512;                 // 512
        int*      gcursor = gbase + 512;                // 512
        float*    als2    = ws + 1552;                  // N
        float*    ald2    = als2 + N;                   // N
        float*    h2      = ald2 + N;                   // 8N
        unsigned* pairs   = (unsigned*)(h2 + 8 * (size_t)N);  // E

        hipMemsetAsync(gcnt, 0, 512 * sizeof(int), stream);
        prep_consts<<<1, 64, 0, stream>>>(W1, as1, ad1, consts);
        bucket_hist<<<512, 256, 0, stream>>>(ei, gcnt, E);
        scan_init<<<1, 512, 0, stream>>>(gcnt, gbase, gcursor);
        bucket_scatter<<<512, 256, 0, stream>>>(ei, gcursor, pairs, E);
        l1_win<<<NB * 4, 256, 0, stream>>>(x, gbase, gcnt, pairs, consts,
                                           W1, b1, W2, as2, ad2, h2, als2, ald2, N);
        l2_win<<<NB * 4, 256, 0, stream>>>(gbase, gcnt, pairs, als2, ald2, h2, b2, out, N);
    } else {
        // fallback: R2 atomic path (10.8 MB ws, known-correct)
        float* consts = ws;
        float* s1   = ws + 16;
        float* t1   = s1 + 4 * (size_t)N;
        float* h2   = t1 + 4 * (size_t)N;
        float* als2 = h2 + 8 * (size_t)N;
        float* ald2 = als2 + (size_t)N;
        float* s2   = ald2 + (size_t)N;
        float* acc2 = s2 + (size_t)N;

        hipMemsetAsync(ws, 0, (16 + 8 * (size_t)N) * sizeof(float), stream);
        hipMemsetAsync(s2, 0, 9 * (size_t)N * sizeof(float), stream);
        prep_consts<<<1, 64, 0, stream>>>(W1, as1, ad1, consts);
        int total = E + N;
        edge_pass1<<<(total + 255) / 256, 256, 0, stream>>>(ei, x, consts, s1, t1, E, N);
        node_mid<<<(N + 255) / 256, 256, 0, stream>>>(s1, t1, W1, b1, W2, as2, ad2, h2, als2, ald2, N);
        edge_pass2<<<(total + 255) / 256, 256, 0, stream>>>(ei, als2, ald2, h2, s2, acc2, E, N);
        node_out<<<(N * 8 + 255) / 256, 256, 0, stream>>>(s2, acc2, b2, out, N);
    }
}